// Round 2
// baseline (275.633 us; speedup 1.0000x reference)
//
#include <hip/hip_runtime.h>

// Problem constants
#define SEQ 2048
#define HID 2048
#define NH 16
#define NKVH 4
#define HDIM 128
#define NB 2
#define MTOT (NB * SEQ)          // 4096 rows
#define QKV_N (NH * HDIM + 2 * NKVH * HDIM)  // 2048 + 512 + 512 = 3072
#define OUT0_ELEMS (NB * SEQ * HID)          // 8,388,608
#define ATTN_ELEMS ((size_t)NB * NH * SEQ * SEQ) // 134,217,728

typedef __bf16 bf16x8 __attribute__((ext_vector_type(8)));
typedef float f32x4 __attribute__((ext_vector_type(4)));

__device__ __forceinline__ unsigned short f2bf(float f) {
  unsigned int u = __float_as_uint(f);
  u += 0x7FFFu + ((u >> 16) & 1u);   // round-to-nearest-even
  return (unsigned short)(u >> 16);
}

// ---------------- f32 -> bf16 elementwise convert (vectorized) ----------------
__global__ void cvt_f32_bf16_k(const float* __restrict__ in,
                               unsigned short* __restrict__ out, int n4) {
  int stride = gridDim.x * blockDim.x;
  for (int i = blockIdx.x * blockDim.x + threadIdx.x; i < n4; i += stride) {
    float4 v = ((const float4*)in)[i];
    ushort4 o;
    o.x = f2bf(v.x); o.y = f2bf(v.y); o.z = f2bf(v.z); o.w = f2bf(v.w);
    ((ushort4*)out)[i] = o;
  }
}

// ---------------- transpose + convert: W (K x N) f32 -> Wt (N x K) bf16 -------
__global__ void transpose_cvt_k(const float* __restrict__ W,
                                unsigned short* __restrict__ Wt, int K, int N) {
  __shared__ float tile[32][33];
  int n0 = blockIdx.x * 32, k0 = blockIdx.y * 32;
  int tx = threadIdx.x, ty = threadIdx.y;  // block (32, 8)
  #pragma unroll
  for (int r = 0; r < 32; r += 8)
    tile[ty + r][tx] = W[(size_t)(k0 + ty + r) * N + n0 + tx];
  __syncthreads();
  #pragma unroll
  for (int r = 0; r < 32; r += 8)
    Wt[(size_t)(n0 + ty + r) * K + k0 + tx] = f2bf(tile[tx][ty + r]);
}

// ---------------- bf16 MFMA GEMM: C(MxN) = A(MxK) * Bt(NxK)^T  (m97 structure)
// 128x128 tile, 4 waves each owning 64x64 (4x4 frags of 16x16x32), BK=32,
// global_load_lds width-16 staging, 2 barriers per K-step.
__global__ __launch_bounds__(256) void gemm_bt_k(
    const unsigned short* __restrict__ A, const unsigned short* __restrict__ Bt,
    float* __restrict__ C, int M, int N, int K) {
  __shared__ unsigned short As[128 * 32];
  __shared__ unsigned short Bs[128 * 32];
  const int t = threadIdx.x;
  const int row0 = blockIdx.y << 7;
  const int col0 = blockIdx.x << 7;
  const int lane = t & 63;
  const int wave = t >> 6;
  const int wr = (wave >> 1) << 6;   // wave row offset within tile
  const int wc = (wave & 1) << 6;    // wave col offset within tile
  const int lrow = lane & 15;
  const int kofs = (lane >> 4) << 3; // 8*(lane/16)

  f32x4 acc[4][4];
  #pragma unroll
  for (int a = 0; a < 4; ++a)
    #pragma unroll
    for (int b = 0; b < 4; ++b)
      #pragma unroll
      for (int r = 0; r < 4; ++r) acc[a][b][r] = 0.f;

  // staging: 512 chunks of 16B per tile (128 rows x 32 cols bf16); 256 threads x 2
  const int ar0 = t >> 2, ac0 = (t & 3) << 3;
  const int ar1 = ar0 + 64;

  const unsigned short* Ab = A + (size_t)row0 * K;
  const unsigned short* Bb = Bt + (size_t)col0 * K;

  const int nk = K >> 5;
  for (int kt = 0; kt < nk; ++kt) {
    const int k0 = kt << 5;
    if (kt) __syncthreads();   // previous compute done before overwrite
    __builtin_amdgcn_global_load_lds(
        (const __attribute__((address_space(1))) void*)(Ab + (size_t)ar0 * K + k0 + ac0),
        (__attribute__((address_space(3))) void*)(As + t * 8), 16, 0, 0);
    __builtin_amdgcn_global_load_lds(
        (const __attribute__((address_space(1))) void*)(Ab + (size_t)ar1 * K + k0 + ac0),
        (__attribute__((address_space(3))) void*)(As + (t + 256) * 8), 16, 0, 0);
    __builtin_amdgcn_global_load_lds(
        (const __attribute__((address_space(1))) void*)(Bb + (size_t)ar0 * K + k0 + ac0),
        (__attribute__((address_space(3))) void*)(Bs + t * 8), 16, 0, 0);
    __builtin_amdgcn_global_load_lds(
        (const __attribute__((address_space(1))) void*)(Bb + (size_t)ar1 * K + k0 + ac0),
        (__attribute__((address_space(3))) void*)(Bs + (t + 256) * 8), 16, 0, 0);
    __syncthreads();           // drain (compiler emits vmcnt(0) before barrier)

    bf16x8 af[4], bfr[4];
    #pragma unroll
    for (int mf = 0; mf < 4; ++mf)
      af[mf] = *(const bf16x8*)(As + ((wr + mf * 16 + lrow) << 5) + kofs);
    #pragma unroll
    for (int nf = 0; nf < 4; ++nf)
      bfr[nf] = *(const bf16x8*)(Bs + ((wc + nf * 16 + lrow) << 5) + kofs);
    #pragma unroll
    for (int mf = 0; mf < 4; ++mf)
      #pragma unroll
      for (int nf = 0; nf < 4; ++nf)
        acc[mf][nf] = __builtin_amdgcn_mfma_f32_16x16x32_bf16(af[mf], bfr[nf],
                                                              acc[mf][nf], 0, 0, 0);
  }

  // epilogue: D mapping col=lane&15, row=(lane>>4)*4+reg  [measured m89/m91]
  const int cr = row0 + wr + ((lane >> 4) << 2);
  const int cc = col0 + wc + (lane & 15);
  #pragma unroll
  for (int mf = 0; mf < 4; ++mf)
    #pragma unroll
    for (int nf = 0; nf < 4; ++nf)
      #pragma unroll
      for (int r = 0; r < 4; ++r)
        C[(size_t)(cr + mf * 16 + r) * N + cc + nf * 16] = acc[mf][nf][r];
}

// ---------------- RoPE in-place on QKV f32 buffer -----------------------------
// QKV: [4096][3072]; q cols [0,2048) (16 heads), k cols [2048,2560) (4 heads)
__global__ void rope_k(float* __restrict__ QKV, const float* __restrict__ cosT,
                       const float* __restrict__ sinT) {
  int idx = blockIdx.x * 256 + threadIdx.x;   // 4096 * 1280 pairs
  int m = idx / 1280;
  int p = idx - m * 1280;
  int s = m & (SEQ - 1);
  int tt, col;
  if (p < 1024) { tt = p & 63; col = (p >> 6) * HDIM + 2 * tt; }
  else { int pk = p - 1024; tt = pk & 63; col = 2048 + (pk >> 6) * HDIM + 2 * tt; }
  size_t base = (size_t)m * QKV_N + col;
  float a = QKV[base], b = QKV[base + 1];
  float c = cosT[s * 64 + tt], sn = sinT[s * 64 + tt];
  QKV[base] = a * c - b * sn;
  QKV[base + 1] = a * sn + b * c;
}

// ---------------- sliding-window attention: 1 wave per (b,i,h) ----------------
__global__ void attn_k(const float* __restrict__ QKV, unsigned short* __restrict__ AO,
                       float* __restrict__ attn_out) {
  int unit = blockIdx.x * 4 + (threadIdx.x >> 6);  // (b*S + i)*H + h
  int lane = threadIdx.x & 63;
  int h = unit & (NH - 1);
  int mi = unit >> 4;            // b*S + i
  int i = mi & (SEQ - 1);
  int kh = h >> 2;               // GQA: repeat -> h//4
  const float SCALE = 0.08838834764831845f;  // 1/sqrt(128)

  const float* qp = QKV + (size_t)mi * QKV_N + h * HDIM;
  float q0 = qp[lane], q1 = qp[lane + 64];

  float sc[3];
  #pragma unroll
  for (int jj = 0; jj < 3; ++jj) {
    int j = i - 2 + jj;
    float d = -1e30f;
    if (j >= 0) {   // wave-uniform branch
      const float* kp = QKV + (size_t)(mi - i + j) * QKV_N + 2048 + kh * HDIM;
      float part = q0 * kp[lane] + q1 * kp[lane + 64];
      #pragma unroll
      for (int o = 32; o; o >>= 1) part += __shfl_xor(part, o, 64);
      d = part * SCALE;
    }
    sc[jj] = d;
  }
  float mx = fmaxf(fmaxf(sc[0], sc[1]), sc[2]);
  float p0 = __expf(sc[0] - mx), p1 = __expf(sc[1] - mx), p2 = __expf(sc[2] - mx);
  float inv = 1.0f / (p0 + p1 + p2);
  float aw[3] = {p0 * inv, p1 * inv, p2 * inv};

  float o0 = 0.f, o1 = 0.f;
  #pragma unroll
  for (int jj = 0; jj < 3; ++jj) {
    int j = i - 2 + jj;
    if (j >= 0) {
      const float* vp = QKV + (size_t)(mi - i + j) * QKV_N + 2560 + kh * HDIM;
      o0 += aw[jj] * vp[lane];
      o1 += aw[jj] * vp[lane + 64];
    }
  }
  size_t ao_base = (size_t)mi * HID + h * HDIM;
  AO[ao_base + lane] = f2bf(o0);
  AO[ao_base + lane + 64] = f2bf(o1);

  if (lane < 3) {  // scatter the <=3 nonzero attn probs
    int j = i - 2 + lane;
    if (j >= 0) {
      int b = mi >> 11;
      size_t off = (((size_t)(b * NH + h) * SEQ) + i) * SEQ + j;
      attn_out[off] = aw[lane];
    }
  }
}

extern "C" void kernel_launch(void* const* d_in, const int* in_sizes, int n_in,
                              void* d_out, int out_size, void* d_ws, size_t ws_size,
                              hipStream_t stream) {
  const float* x    = (const float*)d_in[0];
  const float* wq   = (const float*)d_in[1];
  const float* wk   = (const float*)d_in[2];
  const float* wv   = (const float*)d_in[3];
  const float* wo   = (const float*)d_in[4];
  const float* cosT = (const float*)d_in[5];
  const float* sinT = (const float*)d_in[6];

  float* out  = (float*)d_out;            // [4096][2048] f32
  float* attn = out + OUT0_ELEMS;         // [2][16][2048][2048] f32

  // workspace layout (total ~100 MB)
  char* ws = (char*)d_ws;
  unsigned short* Xbf   = (unsigned short*)ws;  ws += (size_t)MTOT * HID * 2;       // 16.8 MB
  unsigned short* Wqkvt = (unsigned short*)ws;  ws += (size_t)QKV_N * HID * 2;      // 12.6 MB
  unsigned short* Wot   = (unsigned short*)ws;  ws += (size_t)HID * HID * 2;        // 8.4 MB
  float*          QKV   = (float*)ws;           ws += (size_t)MTOT * QKV_N * 4;     // 50.3 MB
  unsigned short* AO    = (unsigned short*)ws;                                      // 16.8 MB

  // zero the (mostly-sparse) dense attn output every call
  hipMemsetAsync(attn, 0, ATTN_ELEMS * sizeof(float), stream);

  // convert x to bf16
  cvt_f32_bf16_k<<<2048, 256, 0, stream>>>(x, Xbf, MTOT * HID / 4);

  // transpose+convert weights into B^T bf16 layouts
  dim3 tb(32, 8);
  transpose_cvt_k<<<dim3(64, 64), tb, 0, stream>>>(wq, Wqkvt, HID, 2048);
  transpose_cvt_k<<<dim3(16, 64), tb, 0, stream>>>(wk, Wqkvt + (size_t)2048 * HID, HID, 512);
  transpose_cvt_k<<<dim3(16, 64), tb, 0, stream>>>(wv, Wqkvt + (size_t)2560 * HID, HID, 512);
  transpose_cvt_k<<<dim3(64, 64), tb, 0, stream>>>(wo, Wot, HID, 2048);

  // fused QKV projection: [4096,2048] x [2048,3072] -> [4096,3072] f32
  gemm_bt_k<<<dim3(QKV_N / 128, MTOT / 128), 256, 0, stream>>>(Xbf, Wqkvt, QKV,
                                                               MTOT, QKV_N, HID);
  // RoPE q + k in place
  rope_k<<<MTOT * 1280 / 256, 256, 0, stream>>>(QKV, cosT, sinT);

  // sliding-window attention (+ sparse attn scatter, AO in bf16)
  attn_k<<<MTOT * NH / 4, 256, 0, stream>>>(QKV, AO, attn);

  // output projection: [4096,2048] x [2048,2048] -> d_out f32
  gemm_bt_k<<<dim3(HID / 128, MTOT / 128), 256, 0, stream>>>(AO, Wot, out,
                                                             MTOT, HID, HID);
}